// Round 1
// baseline (279.420 us; speedup 1.0000x reference)
//
#include <hip/hip_runtime.h>

// CapsuleLayer dynamic routing, MI355X fp32.
// x: [B=64, N=2048, I=8], W: [J=32, N=2048, D=16, I=8], out v: [B=64, J=32, D=16]
//
// Key identity: routing logits b_t = u_hat . (v_0 + ... + v_{t-1}), so u_hat
// (256 MB) is never materialized — each phase recomputes it in registers from
// x + W (36 MB, L3-resident). Only tiny partial-s [chunks][B][J][D] and the
// cumulative V [B][J][D] live in ws (~8.5 MB).

#define BB_ 64
#define NN_ 2048
#define II_ 8
#define JJ_ 32
#define DD_ 16
#define CCHUNKS 64
#define CHUNK (NN_ / CCHUNKS) /* 32 n's per block */
#define EPS_ 1e-7f

#define PARTIAL_FLOATS (CCHUNKS * BB_ * JJ_ * DD_) /* 2M floats = 8 MB */

// Phase kernel: block = (b-group of 8) x (n-chunk of 32). 256 threads:
// thread (j = tid>>3, p = tid&7) owns output caps j, dims d in {2p, 2p+1},
// for all 8 b's. s-partials accumulate in registers across the chunk.
template <int PHASE>
__global__ __launch_bounds__(256) void caps_phase(
    const float* __restrict__ x, const float* __restrict__ W,
    const float* __restrict__ V, float* __restrict__ partial) {
  const int tid = threadIdx.x;
  const int j = tid >> 3;
  const int p = tid & 7;
  const int bg = blockIdx.x & 7;
  const int chunk = blockIdx.x >> 3;
  const int b0 = bg * 8;
  const int n0 = chunk * CHUNK;

  __shared__ __align__(16) float xs[8 * CHUNK * 8]; // [b][nl][i], 8 KB
  __shared__ float lmat[8][JJ_];
  __shared__ float cmat[8][JJ_];

  // Stage x slab for this (b-group, chunk): 512 float4's.
  {
    const float4* xg = (const float4*)x;
    float4* xs4 = (float4*)xs;
    for (int q = tid; q < 8 * CHUNK * 2; q += 256) {
      const int b = q / (CHUNK * 2);
      const int r = q % (CHUNK * 2);
      const int nl = r >> 1;
      const int ih = r & 1;
      xs4[q] = xg[(size_t)(b0 + b) * (NN_ * II_ / 4) + (size_t)(n0 + nl) * 2 + ih];
    }
  }

  // This thread's V fragment: V[b0+b][j][2p], V[b0+b][j][2p+1] for 8 b's.
  float v0r[8], v1r[8];
  if (PHASE > 0) {
    for (int b = 0; b < 8; ++b) {
      const float2 vv = *(const float2*)&V[((size_t)(b0 + b) * JJ_ + j) * DD_ + 2 * p];
      v0r[b] = vv.x;
      v1r[b] = vv.y;
    }
  }

  __syncthreads();

  float s0[8], s1[8];
#pragma unroll
  for (int b = 0; b < 8; ++b) {
    s0[b] = 0.f;
    s1[b] = 0.f;
  }

  // W[j][n][d][i] flat: j*N*D*I + n*D*I + d*I + i. Thread reads d=2p,2p+1:
  // 16 consecutive floats at j*262144 + n*128 + p*16.
  const size_t wbase = (size_t)j * (NN_ * DD_ * II_) + (size_t)p * 16;

  for (int nl = 0; nl < CHUNK; ++nl) {
    const int n = n0 + nl;
    const float4* wp = (const float4*)(W + wbase + (size_t)n * (DD_ * II_));
    const float4 w0 = wp[0], w1 = wp[1], w2 = wp[2], w3 = wp[3];

    float u0[8], u1[8];
#pragma unroll
    for (int b = 0; b < 8; ++b) {
      const float4 xa = *(const float4*)&xs[(b * CHUNK + nl) * 8];
      const float4 xb = *(const float4*)&xs[(b * CHUNK + nl) * 8 + 4];
      u0[b] = w0.x * xa.x + w0.y * xa.y + w0.z * xa.z + w0.w * xa.w +
              w1.x * xb.x + w1.y * xb.y + w1.z * xb.z + w1.w * xb.w;
      u1[b] = w2.x * xa.x + w2.y * xa.y + w2.z * xa.z + w2.w * xa.w +
              w3.x * xb.x + w3.y * xb.y + w3.z * xb.z + w3.w * xb.w;
    }

    if (PHASE == 0) {
      // softmax(0) over J is exactly uniform -> just sum u_hat (scale at store)
#pragma unroll
      for (int b = 0; b < 8; ++b) {
        s0[b] += u0[b];
        s1[b] += u1[b];
      }
    } else {
      // logits l[b][j] = sum_d u_hat * V ; partial over this thread's 2 d's,
      // butterfly-reduce over the 8 p-lanes (aligned 8-lane groups).
#pragma unroll
      for (int b = 0; b < 8; ++b) {
        float lp = u0[b] * v0r[b] + u1[b] * v1r[b];
        lp += __shfl_xor(lp, 1);
        lp += __shfl_xor(lp, 2);
        lp += __shfl_xor(lp, 4);
        if (p == 0) lmat[b][j] = lp;
      }
      __syncthreads();
      // softmax over j: remap tid -> (bb = tid>>5, jj = tid&31); 32-lane groups
      {
        const int bb = tid >> 5;
        const int jj = tid & 31;
        const float l = lmat[bb][jj];
        float m = l;
        m = fmaxf(m, __shfl_xor(m, 16));
        m = fmaxf(m, __shfl_xor(m, 8));
        m = fmaxf(m, __shfl_xor(m, 4));
        m = fmaxf(m, __shfl_xor(m, 2));
        m = fmaxf(m, __shfl_xor(m, 1));
        const float e = __expf(l - m);
        float sm = e;
        sm += __shfl_xor(sm, 16);
        sm += __shfl_xor(sm, 8);
        sm += __shfl_xor(sm, 4);
        sm += __shfl_xor(sm, 2);
        sm += __shfl_xor(sm, 1);
        cmat[bb][jj] = e / sm;
      }
      __syncthreads();
#pragma unroll
      for (int b = 0; b < 8; ++b) {
        const float c = cmat[b][j]; // broadcast read (all p-lanes same addr)
        s0[b] += c * u0[b];
        s1[b] += c * u1[b];
      }
      // no third sync needed: next iter's lmat write happens after the
      // sync above on every thread (see hazard analysis in journal)
    }
  }

  const float scale = (PHASE == 0) ? (1.0f / 32.0f) : 1.0f;
#pragma unroll
  for (int b = 0; b < 8; ++b) {
    const size_t off =
        ((size_t)chunk * BB_ + (b0 + b)) * (JJ_ * DD_) + j * DD_ + 2 * p;
    *(float2*)&partial[off] = make_float2(s0[b] * scale, s1[b] * scale);
  }
}

// Reduce over chunks + squash. MODE 0: V = v ; 1: V += v ; 2: out = v.
template <int MODE>
__global__ __launch_bounds__(256) void caps_reduce(
    const float* __restrict__ partial, float* __restrict__ V,
    float* __restrict__ out) {
  const int t = blockIdx.x * 256 + threadIdx.x; // [0, B*J*D)
  float s = 0.f;
#pragma unroll 8
  for (int c = 0; c < CCHUNKS; ++c) s += partial[(size_t)c * (BB_ * JJ_ * DD_) + t];
  // sum of squares over d (16 consecutive lanes = one (b,j))
  float ss = s * s;
  ss += __shfl_xor(ss, 1);
  ss += __shfl_xor(ss, 2);
  ss += __shfl_xor(ss, 4);
  ss += __shfl_xor(ss, 8);
  const float v = s / sqrtf(ss + EPS_);
  if (MODE == 0)
    V[t] = v;
  else if (MODE == 1)
    V[t] += v;
  else
    out[t] = v;
}

extern "C" void kernel_launch(void* const* d_in, const int* in_sizes, int n_in,
                              void* d_out, int out_size, void* d_ws,
                              size_t ws_size, hipStream_t stream) {
  const float* x = (const float*)d_in[0];
  const float* W = (const float*)d_in[1];
  float* out = (float*)d_out;
  float* partial = (float*)d_ws;                 // 8 MB
  float* V = partial + PARTIAL_FLOATS;           // 128 KB

  const dim3 kgrid(8 * CCHUNKS); // 512 blocks x 256 threads
  const dim3 rgrid((BB_ * JJ_ * DD_) / 256); // 128 blocks

  caps_phase<0><<<kgrid, 256, 0, stream>>>(x, W, nullptr, partial);
  caps_reduce<0><<<rgrid, 256, 0, stream>>>(partial, V, out);
  caps_phase<1><<<kgrid, 256, 0, stream>>>(x, W, V, partial);
  caps_reduce<1><<<rgrid, 256, 0, stream>>>(partial, V, out);
  caps_phase<2><<<kgrid, 256, 0, stream>>>(x, W, V, partial);
  caps_reduce<2><<<rgrid, 256, 0, stream>>>(partial, V, out);
}

// Round 2
// 231.364 us; speedup vs baseline: 1.2077x; 1.2077x over previous
//
#include <hip/hip_runtime.h>

// CapsuleLayer dynamic routing, MI355X fp32.
// x: [B=64, N=2048, I=8], W: [J=32, N=2048, D=16, I=8], out v: [B=64, J=32, D=16]
//
// b_t = u_hat . (v_0+...+v_{t-1})  =>  u_hat (256 MB) never materialized;
// each phase recomputes it in registers from x + W.
// R2: 16 b's per block (W redundancy 8x -> 4x) + XCD swizzle so the 4 blocks
// sharing a W chunk-slab (256 KB) land on one XCD's L2 (4 MB holds 16 slabs).

#define BB_ 64
#define NN_ 2048
#define II_ 8
#define JJ_ 32
#define DD_ 16
#define NCHUNKS 128
#define CHUNK 16  /* n's per block */
#define BG 16     /* b's per block */
#define NBG (BB_ / BG) /* 4 */
#define EPS_ 1e-7f

#define PARTIAL_FLOATS (NCHUNKS * BB_ * JJ_ * DD_) /* 4M floats = 16.8 MB */

// Phase kernel: 256 threads = (j = tid>>3) x (p = tid&7); thread owns output
// cap j, dims d in {2p,2p+1}, for 16 b's. blockIdx = bg*NCHUNKS + chunk so
// blockIdx%8 == chunk%8 -> same-chunk blocks share an XCD (L2 reuse of W).
template <int PHASE>
__global__ __launch_bounds__(256) void caps_phase(
    const float* __restrict__ x, const float* __restrict__ W,
    const float* __restrict__ V, float* __restrict__ partial) {
  const int tid = threadIdx.x;
  const int j = tid >> 3;
  const int p = tid & 7;
  const int chunk = blockIdx.x & (NCHUNKS - 1);
  const int bg = blockIdx.x >> 7;
  const int b0 = bg * BG;
  const int n0 = chunk * CHUNK;

  __shared__ __align__(16) float xs[BG * CHUNK * II_]; // [b][nl][i], 8 KB
  __shared__ float lmat[BG][JJ_];
  __shared__ float cmat[BG][JJ_];

  // Stage x slab: BG*CHUNK*2 = 512 float4 (x[b] rows are contiguous).
  {
    const float4* xg = (const float4*)x;
    float4* xs4 = (float4*)xs;
    for (int q = tid; q < BG * CHUNK * 2; q += 256) {
      const int b = q >> 5;  // 32 float4 per b
      const int r = q & 31;
      xs4[q] = xg[(size_t)(b0 + b) * (NN_ * II_ / 4) + (size_t)n0 * 2 + r];
    }
  }

  // V fragment: V[b0+b][j][2p..2p+1] for 16 b's (32 VGPRs).
  float v0r[BG], v1r[BG];
  if (PHASE > 0) {
#pragma unroll
    for (int b = 0; b < BG; ++b) {
      const float2 vv =
          *(const float2*)&V[((size_t)(b0 + b) * JJ_ + j) * DD_ + 2 * p];
      v0r[b] = vv.x;
      v1r[b] = vv.y;
    }
  }

  __syncthreads();

  float s0[BG], s1[BG];
#pragma unroll
  for (int b = 0; b < BG; ++b) {
    s0[b] = 0.f;
    s1[b] = 0.f;
  }

  // W[j][n][d][i]: thread reads 16 consecutive floats at j*262144 + n*128 + p*16.
  const float* wp = W + (size_t)j * (NN_ * DD_ * II_) + (size_t)n0 * (DD_ * II_) +
                    (size_t)p * 16;
  float4 wc0 = ((const float4*)wp)[0];
  float4 wc1 = ((const float4*)wp)[1];
  float4 wc2 = ((const float4*)wp)[2];
  float4 wc3 = ((const float4*)wp)[3];

  for (int nl = 0; nl < CHUNK; ++nl) {
    // Register double-buffer: prefetch next n's W while computing this one.
    const int nn = (nl + 1 < CHUNK) ? nl + 1 : nl;
    const float4* np_ = (const float4*)(wp + (size_t)nn * (DD_ * II_));
    const float4 wn0 = np_[0], wn1 = np_[1], wn2 = np_[2], wn3 = np_[3];

    float u0[BG], u1[BG];
#pragma unroll
    for (int b = 0; b < BG; ++b) {
      const float4 xa = *(const float4*)&xs[(b * CHUNK + nl) * II_];
      const float4 xb = *(const float4*)&xs[(b * CHUNK + nl) * II_ + 4];
      u0[b] = wc0.x * xa.x + wc0.y * xa.y + wc0.z * xa.z + wc0.w * xa.w +
              wc1.x * xb.x + wc1.y * xb.y + wc1.z * xb.z + wc1.w * xb.w;
      u1[b] = wc2.x * xa.x + wc2.y * xa.y + wc2.z * xa.z + wc2.w * xa.w +
              wc3.x * xb.x + wc3.y * xb.y + wc3.z * xb.z + wc3.w * xb.w;
    }

    if (PHASE == 0) {
      // softmax(0) over J is uniform -> plain sum (scale at store).
#pragma unroll
      for (int b = 0; b < BG; ++b) {
        s0[b] += u0[b];
        s1[b] += u1[b];
      }
    } else {
      // logits l[b][j] = sum_d u_hat*V: 2-elem partial, butterfly over 8 p-lanes
#pragma unroll
      for (int b = 0; b < BG; ++b) {
        float lp = u0[b] * v0r[b] + u1[b] * v1r[b];
        lp += __shfl_xor(lp, 1);
        lp += __shfl_xor(lp, 2);
        lp += __shfl_xor(lp, 4);
        if (p == 0) lmat[b][j] = lp;
      }
      __syncthreads();
      // softmax over j (32 entries) x 16 b; each thread handles 2 entries.
      // |logit| <= ~1.2 (|u|~0.6, v unit-ish, <=2 accumulated v's): exp safe
      // without max subtraction.
      {
        const int jj = tid & 31;
        const int bb = tid >> 5;  // entry0 [bb][jj], entry1 [bb+8][jj]
        const float e0 = __expf(lmat[bb][jj]);
        const float e1 = __expf(lmat[bb + 8][jj]);
        float m0 = e0, m1 = e1;
        m0 += __shfl_xor(m0, 16);
        m1 += __shfl_xor(m1, 16);
        m0 += __shfl_xor(m0, 8);
        m1 += __shfl_xor(m1, 8);
        m0 += __shfl_xor(m0, 4);
        m1 += __shfl_xor(m1, 4);
        m0 += __shfl_xor(m0, 2);
        m1 += __shfl_xor(m1, 2);
        m0 += __shfl_xor(m0, 1);
        m1 += __shfl_xor(m1, 1);
        cmat[bb][jj] = e0 * __builtin_amdgcn_rcpf(m0);
        cmat[bb + 8][jj] = e1 * __builtin_amdgcn_rcpf(m1);
      }
      __syncthreads();
#pragma unroll
      for (int b = 0; b < BG; ++b) {
        const float c = cmat[b][j];  // broadcast (all p-lanes same addr)
        s0[b] += c * u0[b];
        s1[b] += c * u1[b];
      }
      // no 3rd sync needed: next iter writes lmat (!= cmat); cmat(t+1) writes
      // are gated behind sync1(t+1) which waits for all cmat(t) readers.
    }

    wc0 = wn0;
    wc1 = wn1;
    wc2 = wn2;
    wc3 = wn3;
  }

  const float scale = (PHASE == 0) ? (1.0f / 32.0f) : 1.0f;
#pragma unroll
  for (int b = 0; b < BG; ++b) {
    const size_t off =
        ((size_t)chunk * BB_ + (b0 + b)) * (JJ_ * DD_) + j * DD_ + 2 * p;
    *(float2*)&partial[off] = make_float2(s0[b] * scale, s1[b] * scale);
  }
}

// Reduce over chunks + squash. MODE 0: V = v ; 1: V += v ; 2: out = v.
template <int MODE>
__global__ __launch_bounds__(256) void caps_reduce(
    const float* __restrict__ partial, float* __restrict__ V,
    float* __restrict__ out) {
  const int t = blockIdx.x * 256 + threadIdx.x;  // [0, B*J*D)
  float s = 0.f;
#pragma unroll 8
  for (int c = 0; c < NCHUNKS; ++c)
    s += partial[(size_t)c * (BB_ * JJ_ * DD_) + t];
  // sum of squares over d (16 consecutive lanes = one (b,j))
  float ss = s * s;
  ss += __shfl_xor(ss, 1);
  ss += __shfl_xor(ss, 2);
  ss += __shfl_xor(ss, 4);
  ss += __shfl_xor(ss, 8);
  const float v = s / sqrtf(ss + EPS_);
  if (MODE == 0)
    V[t] = v;
  else if (MODE == 1)
    V[t] += v;
  else
    out[t] = v;
}

extern "C" void kernel_launch(void* const* d_in, const int* in_sizes, int n_in,
                              void* d_out, int out_size, void* d_ws,
                              size_t ws_size, hipStream_t stream) {
  const float* x = (const float*)d_in[0];
  const float* W = (const float*)d_in[1];
  float* out = (float*)d_out;
  float* partial = (float*)d_ws;        // 16.8 MB
  float* V = partial + PARTIAL_FLOATS;  // 128 KB

  const dim3 kgrid(NBG * NCHUNKS);            // 512 blocks x 256 threads
  const dim3 rgrid((BB_ * JJ_ * DD_) / 256);  // 128 blocks

  caps_phase<0><<<kgrid, 256, 0, stream>>>(x, W, nullptr, partial);
  caps_reduce<0><<<rgrid, 256, 0, stream>>>(partial, V, out);
  caps_phase<1><<<kgrid, 256, 0, stream>>>(x, W, V, partial);
  caps_reduce<1><<<rgrid, 256, 0, stream>>>(partial, V, out);
  caps_phase<2><<<kgrid, 256, 0, stream>>>(x, W, V, partial);
  caps_reduce<2><<<rgrid, 256, 0, stream>>>(partial, V, out);
}

// Round 4
// 213.972 us; speedup vs baseline: 1.3059x; 1.0813x over previous
//
#include <hip/hip_runtime.h>

// CapsuleLayer dynamic routing, MI355X fp32.
// x: [B=64, N=2048, I=8], W: [J=32, N=2048, D=16, I=8], out v: [B=64, J=32, D=16]
//
// b_t = u_hat . (v_0+...+v_{t-1})  =>  u_hat (256 MB) never materialized;
// each phase recomputes it in registers from x + W (L2/L3-resident, R2 proved
// FETCH=19MB). R3/R4: evacuate the LDS pipe (R2's bottleneck):
//   - x read via wave-uniform global loads instead of ds_read broadcasts
//   - logit d-reduce via DPP XOR-BUTTERFLY (R3 bug: row_shr puts the sum in
//     lane 7, not lane 0; butterfly is direction-free — all lanes get the sum)
//   - softmax j-sum via DPP xor{1,2,7,8} + one shfl_xor(16)

#define BB_ 64
#define NN_ 2048
#define II_ 8
#define JJ_ 32
#define DD_ 16
#define NCHUNKS 128
#define CHUNK 16  /* n's per block */
#define BG 16     /* b's per block */
#define NBG (BB_ / BG) /* 4 */
#define EPS_ 1e-7f

#define PARTIAL_FLOATS (NCHUNKS * BB_ * JJ_ * DD_) /* 4M floats = 16.8 MB */

// DPP helpers (VALU-pipe cross-lane). CTRL must be an immediate.
template <int CTRL>
__device__ __forceinline__ float dpp_add(float v) {
  const int s = __builtin_amdgcn_update_dpp(
      0, __builtin_bit_cast(int, v), CTRL, 0xf, 0xf, true);
  return v + __builtin_bit_cast(float, s);
}
#define DPP_QP_XOR1 0xB1      /* quad_perm [1,0,3,2]  : lane ^ 1 */
#define DPP_QP_XOR2 0x4E      /* quad_perm [2,3,0,1]  : lane ^ 2 */
#define DPP_HALF_MIRROR 0x141 /* mirror within 8      : lane ^ 7 */
#define DPP_ROR8 0x128        /* row_ror:8 (16-lane)  : lane ^ 8 */

// Phase kernel: 256 threads = (j = tid>>3) x (p = tid&7); thread owns output
// cap j, dims d in {2p,2p+1}, for 16 b's. blockIdx = bg*NCHUNKS + chunk so
// blockIdx%8 == chunk%8 -> same-chunk blocks share an XCD (L2 reuse of W).
template <int PHASE>
__global__ __launch_bounds__(256, 2) void caps_phase(
    const float* __restrict__ x, const float* __restrict__ W,
    const float* __restrict__ V, float* __restrict__ partial) {
  const int tid = threadIdx.x;
  const int j = tid >> 3;
  const int p = tid & 7;
  const int chunk = blockIdx.x & (NCHUNKS - 1);
  const int bg = blockIdx.x >> 7;
  const int b0 = bg * BG;
  const int n0 = chunk * CHUNK;

  __shared__ float lmat[BG][JJ_];
  __shared__ float cmat[BG][JJ_];

  // V fragment: V[b0+b][j][2p..2p+1] for 16 b's (32 VGPRs).
  float v0r[BG], v1r[BG];
  if (PHASE > 0) {
#pragma unroll
    for (int b = 0; b < BG; ++b) {
      const float2 vv =
          *(const float2*)&V[((size_t)(b0 + b) * JJ_ + j) * DD_ + 2 * p];
      v0r[b] = vv.x;
      v1r[b] = vv.y;
    }
  }

  float s0[BG], s1[BG];
#pragma unroll
  for (int b = 0; b < BG; ++b) {
    s0[b] = 0.f;
    s1[b] = 0.f;
  }

  // W[j][n][d][i]: thread reads 16 consecutive floats at j*262144 + n*128 + p*16.
  const float* wp = W + (size_t)j * (NN_ * DD_ * II_) + (size_t)n0 * (DD_ * II_) +
                    (size_t)p * 16;
  float4 wc0 = ((const float4*)wp)[0];
  float4 wc1 = ((const float4*)wp)[1];
  float4 wc2 = ((const float4*)wp)[2];
  float4 wc3 = ((const float4*)wp)[3];

  for (int nl = 0; nl < CHUNK; ++nl) {
    const int n = n0 + nl;
    // Register double-buffer: prefetch next n's W while computing this one.
    const int nn = (nl + 1 < CHUNK) ? nl + 1 : nl;
    const float4* np_ = (const float4*)(wp + (size_t)nn * (DD_ * II_));
    const float4 wn0 = np_[0], wn1 = np_[1], wn2 = np_[2], wn3 = np_[3];

    float u0[BG], u1[BG];
#pragma unroll
    for (int b = 0; b < BG; ++b) {
      // Wave-uniform x row (b, n uniform): scalar-load path, no LDS.
      const float4* __restrict__ xr =
          (const float4*)(x + ((size_t)(b0 + b) * NN_ + n) * II_);
      const float4 xa = xr[0];
      const float4 xb = xr[1];
      u0[b] = wc0.x * xa.x + wc0.y * xa.y + wc0.z * xa.z + wc0.w * xa.w +
              wc1.x * xb.x + wc1.y * xb.y + wc1.z * xb.z + wc1.w * xb.w;
      u1[b] = wc2.x * xa.x + wc2.y * xa.y + wc2.z * xa.z + wc2.w * xa.w +
              wc3.x * xb.x + wc3.y * xb.y + wc3.z * xb.z + wc3.w * xb.w;
    }

    if (PHASE == 0) {
      // softmax(0) over J is uniform -> plain sum (scale at store).
#pragma unroll
      for (int b = 0; b < BG; ++b) {
        s0[b] += u0[b];
        s1[b] += u1[b];
      }
    } else {
      // logits l[b][j] = sum_d u_hat*V: 2-elem partial per lane, then xor
      // butterfly over the 8 p-lanes (xor1, xor2, then half_mirror: lane^7
      // == lane^4 contribution once quads are uniform). ALL lanes end with
      // the full sum -> p==0 store is direction-safe (R3 bug fix).
#pragma unroll
      for (int b = 0; b < BG; ++b) {
        float lp = u0[b] * v0r[b] + u1[b] * v1r[b];
        lp = dpp_add<DPP_QP_XOR1>(lp);
        lp = dpp_add<DPP_QP_XOR2>(lp);
        lp = dpp_add<DPP_HALF_MIRROR>(lp);
        if (p == 0) lmat[b][j] = lp;
      }
      __syncthreads();
      // softmax over j (32 entries) x 16 b; each thread handles 2 entries.
      // |logit| <= ~1.5: exp safe without max subtraction (validated R2).
      // j-sum: DPP butterfly xor{1,2,7,8} + one cross-row shfl_xor(16).
      {
        const int jj = tid & 31;
        const int bb = tid >> 5;  // entry0 [bb][jj], entry1 [bb+8][jj]
        float e0 = __expf(lmat[bb][jj]);
        float e1 = __expf(lmat[bb + 8][jj]);
        float m0 = e0, m1 = e1;
        m0 = dpp_add<DPP_QP_XOR1>(m0);
        m1 = dpp_add<DPP_QP_XOR1>(m1);
        m0 = dpp_add<DPP_QP_XOR2>(m0);
        m1 = dpp_add<DPP_QP_XOR2>(m1);
        m0 = dpp_add<DPP_HALF_MIRROR>(m0);
        m1 = dpp_add<DPP_HALF_MIRROR>(m1);
        m0 = dpp_add<DPP_ROR8>(m0);
        m1 = dpp_add<DPP_ROR8>(m1);
        m0 += __shfl_xor(m0, 16);
        m1 += __shfl_xor(m1, 16);
        cmat[bb][jj] = e0 * __builtin_amdgcn_rcpf(m0);
        cmat[bb + 8][jj] = e1 * __builtin_amdgcn_rcpf(m1);
      }
      __syncthreads();
#pragma unroll
      for (int b = 0; b < BG; ++b) {
        const float c = cmat[b][j];  // broadcast (all p-lanes same addr)
        s0[b] += c * u0[b];
        s1[b] += c * u1[b];
      }
      // no 3rd sync needed: next iter writes lmat only after passing the
      // cmat barrier above; all lmat readers finished before that barrier.
    }

    wc0 = wn0;
    wc1 = wn1;
    wc2 = wn2;
    wc3 = wn3;
  }

  const float scale = (PHASE == 0) ? (1.0f / 32.0f) : 1.0f;
#pragma unroll
  for (int b = 0; b < BG; ++b) {
    const size_t off =
        ((size_t)chunk * BB_ + (b0 + b)) * (JJ_ * DD_) + j * DD_ + 2 * p;
    *(float2*)&partial[off] = make_float2(s0[b] * scale, s1[b] * scale);
  }
}

// Reduce over chunks + squash. MODE 0: V = v ; 1: V += v ; 2: out = v.
template <int MODE>
__global__ __launch_bounds__(256) void caps_reduce(
    const float* __restrict__ partial, float* __restrict__ V,
    float* __restrict__ out) {
  const int t = blockIdx.x * 256 + threadIdx.x;  // [0, B*J*D)
  float s = 0.f;
#pragma unroll 8
  for (int c = 0; c < NCHUNKS; ++c)
    s += partial[(size_t)c * (BB_ * JJ_ * DD_) + t];
  // sum of squares over d (16 consecutive lanes = one (b,j))
  float ss = s * s;
  ss += __shfl_xor(ss, 1);
  ss += __shfl_xor(ss, 2);
  ss += __shfl_xor(ss, 4);
  ss += __shfl_xor(ss, 8);
  const float v = s / sqrtf(ss + EPS_);
  if (MODE == 0)
    V[t] = v;
  else if (MODE == 1)
    V[t] += v;
  else
    out[t] = v;
}

extern "C" void kernel_launch(void* const* d_in, const int* in_sizes, int n_in,
                              void* d_out, int out_size, void* d_ws,
                              size_t ws_size, hipStream_t stream) {
  const float* x = (const float*)d_in[0];
  const float* W = (const float*)d_in[1];
  float* out = (float*)d_out;
  float* partial = (float*)d_ws;        // 16.8 MB
  float* V = partial + PARTIAL_FLOATS;  // 128 KB

  const dim3 kgrid(NBG * NCHUNKS);            // 512 blocks x 256 threads
  const dim3 rgrid((BB_ * JJ_ * DD_) / 256);  // 128 blocks

  caps_phase<0><<<kgrid, 256, 0, stream>>>(x, W, nullptr, partial);
  caps_reduce<0><<<rgrid, 256, 0, stream>>>(partial, V, out);
  caps_phase<1><<<kgrid, 256, 0, stream>>>(x, W, V, partial);
  caps_reduce<1><<<rgrid, 256, 0, stream>>>(partial, V, out);
  caps_phase<2><<<kgrid, 256, 0, stream>>>(x, W, V, partial);
  caps_reduce<2><<<rgrid, 256, 0, stream>>>(partial, V, out);
}

// Round 5
// 177.871 us; speedup vs baseline: 1.5709x; 1.2030x over previous
//
#include <hip/hip_runtime.h>

// CapsuleLayer dynamic routing, MI355X fp32.
// x: [B=64, N=2048, I=8], W: [J=32, N=2048, D=16, I=8], out v: [B=64, J=32, D=16]
//
// b_t = u_hat . (v_0+...+v_{t-1})  =>  u_hat (256 MB) never materialized;
// each phase recomputes it in registers from x + W (L2-resident via XCD swizzle,
// FETCH=21MB per phase). R5: occupancy 2->4 blocks/CU (BG 16->8, NBG 4->8,
// grid 512->1024) + v_pk_fma_f32 via float2 ext-vectors (halves VALU issue)
// + reduce grid widened to cover all 256 CUs.

#define BB_ 64
#define NN_ 2048
#define II_ 8
#define JJ_ 32
#define DD_ 16
#define NCHUNKS 128
#define CHUNK 16      /* n's per block */
#define BG 8          /* b's per block */
#define NBG (BB_ / BG) /* 8 */
#define EPS_ 1e-7f

#define PARTIAL_FLOATS (NCHUNKS * BB_ * JJ_ * DD_) /* 4M floats = 16.8 MB */

typedef __attribute__((ext_vector_type(2))) float v2f;

// DPP helpers (VALU-pipe cross-lane). CTRL must be an immediate.
template <int CTRL>
__device__ __forceinline__ float dpp_add(float v) {
  const int s = __builtin_amdgcn_update_dpp(
      0, __builtin_bit_cast(int, v), CTRL, 0xf, 0xf, true);
  return v + __builtin_bit_cast(float, s);
}
#define DPP_QP_XOR1 0xB1      /* quad_perm [1,0,3,2]  : lane ^ 1 */
#define DPP_QP_XOR2 0x4E      /* quad_perm [2,3,0,1]  : lane ^ 2 */
#define DPP_HALF_MIRROR 0x141 /* mirror within 8      : lane ^ 7 */
#define DPP_ROR8 0x128        /* row_ror:8 (16-lane)  : lane ^ 8 */

// Phase kernel: 256 threads = (j = tid>>3) x (p = tid&7); thread owns output
// cap j, dims d in {2p,2p+1}, for 8 b's. blockIdx = bg*NCHUNKS + chunk so
// blockIdx%8 == chunk%8 -> all 8 blocks sharing a W chunk-slab (256 KB) land
// on one XCD (16 slabs x 256 KB = 4 MB = one L2).
template <int PHASE>
__global__ __launch_bounds__(256, 4) void caps_phase(
    const float* __restrict__ x, const float* __restrict__ W,
    const float* __restrict__ V, float* __restrict__ partial) {
  const int tid = threadIdx.x;
  const int j = tid >> 3;
  const int p = tid & 7;
  const int chunk = blockIdx.x & (NCHUNKS - 1);
  const int bg = blockIdx.x >> 7;
  const int b0 = bg * BG;
  const int n0 = chunk * CHUNK;

  __shared__ float lmat[BG][JJ_];
  __shared__ float cmat[BG][JJ_];

  // V fragment: V[b0+b][j][2p..2p+1] for 8 b's.
  float v0r[BG], v1r[BG];
  if (PHASE > 0) {
#pragma unroll
    for (int b = 0; b < BG; ++b) {
      const float2 vv =
          *(const float2*)&V[((size_t)(b0 + b) * JJ_ + j) * DD_ + 2 * p];
      v0r[b] = vv.x;
      v1r[b] = vv.y;
    }
  }

  v2f s[BG];
#pragma unroll
  for (int b = 0; b < BG; ++b) s[b] = (v2f)(0.f);

  // W[j][n][d][i]: thread reads 16 consecutive floats at j*262144 + n*128 + p*16.
  const float* wp = W + (size_t)j * (NN_ * DD_ * II_) + (size_t)n0 * (DD_ * II_) +
                    (size_t)p * 16;
  float4 wc0 = ((const float4*)wp)[0];
  float4 wc1 = ((const float4*)wp)[1];
  float4 wc2 = ((const float4*)wp)[2];
  float4 wc3 = ((const float4*)wp)[3];

  for (int nl = 0; nl < CHUNK; ++nl) {
    const int n = n0 + nl;
    // Register double-buffer: prefetch next n's W while computing this one.
    const int nn = (nl + 1 < CHUNK) ? nl + 1 : nl;
    const float4* np_ = (const float4*)(wp + (size_t)nn * (DD_ * II_));
    const float4 wn0 = np_[0], wn1 = np_[1], wn2 = np_[2], wn3 = np_[3];

    // Pack W pairs {W[d0][i], W[d1][i]} once per nl -> v_pk_fma operands.
    v2f wk0 = {wc0.x, wc2.x}, wk1 = {wc0.y, wc2.y};
    v2f wk2 = {wc0.z, wc2.z}, wk3 = {wc0.w, wc2.w};
    v2f wk4 = {wc1.x, wc3.x}, wk5 = {wc1.y, wc3.y};
    v2f wk6 = {wc1.z, wc3.z}, wk7 = {wc1.w, wc3.w};

    v2f u[BG];
#pragma unroll
    for (int b = 0; b < BG; ++b) {
      // Wave-uniform x row (b, n uniform): scalar-load path, no LDS.
      const float4* __restrict__ xr =
          (const float4*)(x + ((size_t)(b0 + b) * NN_ + n) * II_);
      const float4 xa = xr[0];
      const float4 xb = xr[1];
      v2f acc = wk0 * xa.x;
      acc += wk1 * xa.y;
      acc += wk2 * xa.z;
      acc += wk3 * xa.w;
      acc += wk4 * xb.x;
      acc += wk5 * xb.y;
      acc += wk6 * xb.z;
      acc += wk7 * xb.w;
      u[b] = acc;
    }

    if (PHASE == 0) {
      // softmax(0) over J is uniform -> plain sum (scale at store).
#pragma unroll
      for (int b = 0; b < BG; ++b) s[b] += u[b];
    } else {
      // logits l[b][j] = sum_d u_hat*V: 2-elem partial per lane, then xor
      // butterfly over the 8 p-lanes (all lanes end with the full sum).
#pragma unroll
      for (int b = 0; b < BG; ++b) {
        float lp = u[b].x * v0r[b] + u[b].y * v1r[b];
        lp = dpp_add<DPP_QP_XOR1>(lp);
        lp = dpp_add<DPP_QP_XOR2>(lp);
        lp = dpp_add<DPP_HALF_MIRROR>(lp);
        if (p == 0) lmat[b][j] = lp;
      }
      __syncthreads();
      // softmax over j (32 entries) x 8 b; threads tid<256 handle 1 entry.
      // |logit| <= ~1.5: exp safe without max subtraction (validated R2/R4).
      // j-sum: DPP butterfly xor{1,2,7,8} + one cross-row shfl_xor(16).
      {
        const int jj = tid & 31;
        const int bb = tid >> 5;  // 8 b's x 32 j's = 256 threads exactly
        float e0 = __expf(lmat[bb][jj]);
        float m0 = e0;
        m0 = dpp_add<DPP_QP_XOR1>(m0);
        m0 = dpp_add<DPP_QP_XOR2>(m0);
        m0 = dpp_add<DPP_HALF_MIRROR>(m0);
        m0 = dpp_add<DPP_ROR8>(m0);
        m0 += __shfl_xor(m0, 16);
        cmat[bb][jj] = e0 * __builtin_amdgcn_rcpf(m0);
      }
      __syncthreads();
#pragma unroll
      for (int b = 0; b < BG; ++b) {
        const float c = cmat[b][j];  // broadcast (all p-lanes same addr)
        s[b] += u[b] * c;            // one v_pk_fma
      }
      // no 3rd sync needed: next iter writes lmat only after passing the
      // cmat barrier above; all lmat readers finished before that barrier.
    }

    wc0 = wn0;
    wc1 = wn1;
    wc2 = wn2;
    wc3 = wn3;
  }

  const float scale = (PHASE == 0) ? (1.0f / 32.0f) : 1.0f;
#pragma unroll
  for (int b = 0; b < BG; ++b) {
    const size_t off =
        ((size_t)chunk * BB_ + (b0 + b)) * (JJ_ * DD_) + j * DD_ + 2 * p;
    *(float2*)&partial[off] = make_float2(s[b].x * scale, s[b].y * scale);
  }
}

// Reduce over chunks + squash. MODE 0: V = v ; 1: V += v ; 2: out = v.
// 256 blocks x 128 threads so every CU gets a block.
template <int MODE>
__global__ __launch_bounds__(128) void caps_reduce(
    const float* __restrict__ partial, float* __restrict__ V,
    float* __restrict__ out) {
  const int t = blockIdx.x * 128 + threadIdx.x;  // [0, B*J*D)
  float s = 0.f;
#pragma unroll 8
  for (int c = 0; c < NCHUNKS; ++c)
    s += partial[(size_t)c * (BB_ * JJ_ * DD_) + t];
  // sum of squares over d (16 consecutive lanes = one (b,j))
  float ss = s * s;
  ss += __shfl_xor(ss, 1);
  ss += __shfl_xor(ss, 2);
  ss += __shfl_xor(ss, 4);
  ss += __shfl_xor(ss, 8);
  const float v = s / sqrtf(ss + EPS_);
  if (MODE == 0)
    V[t] = v;
  else if (MODE == 1)
    V[t] += v;
  else
    out[t] = v;
}

extern "C" void kernel_launch(void* const* d_in, const int* in_sizes, int n_in,
                              void* d_out, int out_size, void* d_ws,
                              size_t ws_size, hipStream_t stream) {
  const float* x = (const float*)d_in[0];
  const float* W = (const float*)d_in[1];
  float* out = (float*)d_out;
  float* partial = (float*)d_ws;        // 16.8 MB
  float* V = partial + PARTIAL_FLOATS;  // 128 KB

  const dim3 kgrid(NBG * NCHUNKS);            // 1024 blocks x 256 threads
  const dim3 rgrid((BB_ * JJ_ * DD_) / 128);  // 256 blocks x 128 threads

  caps_phase<0><<<kgrid, 256, 0, stream>>>(x, W, nullptr, partial);
  caps_reduce<0><<<rgrid, 128, 0, stream>>>(partial, V, out);
  caps_phase<1><<<kgrid, 256, 0, stream>>>(x, W, V, partial);
  caps_reduce<1><<<rgrid, 128, 0, stream>>>(partial, V, out);
  caps_phase<2><<<kgrid, 256, 0, stream>>>(x, W, V, partial);
  caps_reduce<2><<<rgrid, 128, 0, stream>>>(partial, V, out);
}